// Round 19
// baseline (173.360 us; speedup 1.0000x reference)
//
#include <hip/hip_runtime.h>
#include <hip/hip_bf16.h>
#include <stdint.h>

#define B_ 2
#define S_ 2048
#define D_ 2048
#define H_ 32
#define KV_ 8
#define HD_ 64
#define NQKV 3072   // D + 2*KV*HD

typedef __bf16 bf16_t;
typedef __bf16 bf16x8 __attribute__((ext_vector_type(8)));
typedef __bf16 bf16x4 __attribute__((ext_vector_type(4)));
typedef float  f32x4  __attribute__((ext_vector_type(4)));
typedef float  f32x16 __attribute__((ext_vector_type(16)));
typedef unsigned int u32;
typedef u32 u32x4 __attribute__((ext_vector_type(4)));

typedef const __attribute__((address_space(1))) uint32_t* gp1_t;
typedef __attribute__((address_space(3))) uint32_t* lp3_t;

// async global->LDS, 16B per lane. LDS dest is wave-uniform base + lane*16.
__device__ inline void gload_lds16(const void* g, void* l) {
  __builtin_amdgcn_global_load_lds((gp1_t)(uintptr_t)g, (lp3_t)(uint32_t)(uintptr_t)l,
                                   16, 0, 0);
}

__device__ inline u32 pkbf(float a, float b) {
  union { bf16_t h[2]; u32 u; } v;
  v.h[0] = (bf16_t)a; v.h[1] = (bf16_t)b;
  return v.u;
}

// v_permlane32_swap_b32: a = [a_lo, b_lo], b = [a_hi, b_hi]
__device__ inline void pl32swap(u32 &a, u32 &b) {
  asm("v_permlane32_swap_b32 %0, %1" : "+v"(a), "+v"(b));
}

// ---------------- fused prep: x cvt + all 4 weight transposes ----------------
__global__ void prep_all(const float* __restrict__ x, bf16_t* __restrict__ xb,
                         const float* __restrict__ Wq, const float* __restrict__ Wk,
                         const float* __restrict__ Wv, const float* __restrict__ Wo,
                         bf16_t* __restrict__ Wqkvt, bf16_t* __restrict__ Wot) {
  const int id = blockIdx.x;
  const int tid = threadIdx.y * 32 + threadIdx.x;
  if (id < 8192) {                      // x -> bf16 (2097152 float4s)
    const int i = id * 256 + tid;
    float4 v = ((const float4*)x)[i];
    bf16x4 o;
    o[0] = (bf16_t)v.x; o[1] = (bf16_t)v.y; o[2] = (bf16_t)v.z; o[3] = (bf16_t)v.w;
    ((bf16x4*)xb)[i] = o;
    return;
  }
  __shared__ float t[32][33];
  const int wid = id - 8192;
  const float* in; bf16_t* out; int C, roff, bx, by;
  if (wid < 4096)      { in = Wq; out = Wqkvt; C = 2048; roff = 0;    bx = wid & 63;          by = wid >> 6; }
  else if (wid < 5120) { in = Wk; out = Wqkvt; C = 512;  roff = 2048; bx = (wid - 4096) & 15; by = (wid - 4096) >> 4; }
  else if (wid < 6144) { in = Wv; out = Wqkvt; C = 512;  roff = 2560; bx = (wid - 5120) & 15; by = (wid - 5120) >> 4; }
  else                 { in = Wo; out = Wot;   C = 2048; roff = 0;    bx = (wid - 6144) & 63; by = (wid - 6144) >> 6; }
  const int tx = threadIdx.x, ty = threadIdx.y;   // (32,8)
  const int c0 = bx * 32, r0 = by * 32;
#pragma unroll
  for (int j = 0; j < 4; ++j)
    t[ty + j*8][tx] = in[(int64_t)(r0 + ty + j*8) * C + c0 + tx];
  __syncthreads();
#pragma unroll
  for (int j = 0; j < 4; ++j)
    out[(int64_t)(roff + c0 + ty + j*8) * 2048 + r0 + tx] = (bf16_t)t[tx][ty + j*8];
}

// ---------------- fused scatter: RoPE Q/K + V transpose ----------------
#define QSCALE 0.18033688011112042f
__global__ __launch_bounds__(256) void scatter_all(const bf16_t* __restrict__ qkv,
                                                   const float* __restrict__ cosb,
                                                   const float* __restrict__ sinb,
                                                   bf16_t* __restrict__ Q,
                                                   bf16_t* __restrict__ Kr,
                                                   bf16_t* __restrict__ Vt) {
  const int id = blockIdx.x;
  const int tid = threadIdx.x;
  if (id < 4096) {                       // RoPE rows
    const int row = id;                  // b*S + s
    const int b = row >> 11, s = row & 2047;
    const bf16_t* src = qkv + (int64_t)row * NQKV;
    const float* cs = cosb + s * HD_;
    const float* sn = sinb + s * HD_;
    {                                    // Q
      const int c0 = tid * 8;
      const int d0 = c0 & 63, h = c0 >> 6;
      bf16x8 own = *(const bf16x8*)(src + c0);
      bf16x8 par = *(const bf16x8*)(src + (c0 ^ 32));
      const float sgn = (d0 & 32) ? 1.f : -1.f;
      bf16x8 o;
#pragma unroll
      for (int j = 0; j < 8; ++j) {
        const int d = d0 + j;
        float val = (float)own[j] * cs[d] + sgn * (float)par[j] * sn[d];
        o[j] = (bf16_t)(val * QSCALE);
      }
      *(bf16x8*)(Q + ((int64_t)(b * H_ + h) * S_ + s) * HD_ + d0) = o;
    }
    if (tid < 64) {                      // K
      const int c0 = 2048 + tid * 8;
      const int d0 = (tid * 8) & 63, kvh = tid >> 3;
      bf16x8 own = *(const bf16x8*)(src + c0);
      bf16x8 par = *(const bf16x8*)(src + (c0 ^ 32));
      const float sgn = (d0 & 32) ? 1.f : -1.f;
      bf16x8 o;
#pragma unroll
      for (int j = 0; j < 8; ++j) {
        const int d = d0 + j;
        float val = (float)own[j] * cs[d] + sgn * (float)par[j] * sn[d];
        o[j] = (bf16_t)val;
      }
      *(bf16x8*)(Kr + ((int64_t)(b * KV_ + kvh) * S_ + s) * HD_ + d0) = o;
    }
    return;
  }
  // V transpose tiles
  __shared__ bf16_t t[32][34];
  const int wid = id - 4096;
  const int c0 = (wid & 15) * 32;
  const int s0 = ((wid >> 4) & 63) * 32;
  const int b  = wid >> 10;
  const int tx = tid & 31, ty = tid >> 5;   // (32,8)
#pragma unroll
  for (int j = 0; j < 4; ++j)
    t[ty + j*8][tx] = qkv[(int64_t)(b * S_ + s0 + ty + j*8) * NQKV + 2560 + c0 + tx];
  __syncthreads();
#pragma unroll
  for (int j = 0; j < 4; ++j)
    Vt[(int64_t)(b * 512 + c0 + ty + j*8) * S_ + s0 + tx] = t[tx][ty + j*8];
}

// ---------------- 256-row deep-pipelined GEMM (2-buf, XCD swizzle) ----------------
template <int BN, int EPI, typename OutT>
__global__ __launch_bounds__(512, 2) void gemm256(const bf16_t* __restrict__ A,
                                                  const bf16_t* __restrict__ Bt,
                                                  OutT* __restrict__ Cout,
                                                  int N, int K) {
  constexpr int NB = BN / 64;
  constexpr int LT = 4 + NB;
  constexpr int WCOLS = BN / 4;
  constexpr int NF = WCOLS / 16;

  __shared__ bf16_t As[2][256 * 64];
  __shared__ bf16_t Bs[2][BN * 64];

  const int tid = threadIdx.x;
  const int w = tid >> 6, lane = tid & 63;
  const int l15 = lane & 15, l4 = lane >> 4;
  const int wr = w >> 2, wc = w & 3;

  const int nX = gridDim.x;
  const int lin = blockIdx.y * nX + blockIdx.x;
  const int cpx = (nX * gridDim.y) >> 3;
  const int swz = (lin & 7) * cpx + (lin >> 3);
  const int bm = (swz / nX) * 256, bn = (swz % nX) * BN;

  const int rw = w * 8 + (lane >> 3);
  const int srcg = ((lane & 7) ^ ((lane >> 3) & 7)) << 3;
  const bf16_t* PA[4];
  const bf16_t* PB[NB];
#pragma unroll
  for (int L = 0; L < 4; ++L)
    PA[L] = A + (int64_t)(bm + L * 64 + rw) * K + srcg;
#pragma unroll
  for (int L = 0; L < NB; ++L)
    PB[L] = Bt + (int64_t)(bn + L * 64 + rw) * K + srcg;

  const int NK = K >> 6;
  const int xr = l15 & 7;
  const int g0 = (l4 ^ xr) << 3;
  const int g1 = ((4 + l4) ^ xr) << 3;

  f32x4 acc[8][NF] = {};

  auto stage = [&](int s, int buf, int toff) {
    if (s < 4) gload_lds16(PA[s] + toff, &As[buf][s * 4096 + w * 512]);
    else       gload_lds16(PB[s - 4] + toff, &Bs[buf][(s - 4) * 4096 + w * 512]);
  };

#pragma unroll
  for (int s = 0; s < LT; ++s) stage(s, 0, 0);
  asm volatile("s_waitcnt vmcnt(0)" ::: "memory");
  __syncthreads();

  for (int t = 0; t < NK; ++t) {
    const int p = t & 1;
    const bool more = (t + 1) < NK;
    const int toff = (t + 1) << 6;
    const bf16_t* Ab = &As[p][0];
    const bf16_t* Bb = &Bs[p][0];

    bf16x8 ball[NF][2];
#pragma unroll
    for (int nn = 0; nn < NF; ++nn) {
      const int rb = wc * WCOLS + nn * 16 + l15;
      ball[nn][0] = *(const bf16x8*)(Bb + rb * 64 + g0);
      ball[nn][1] = *(const bf16x8*)(Bb + rb * 64 + g1);
    }

#pragma unroll
    for (int mh = 0; mh < 2; ++mh) {
      if (more) {
        const int sb = mh * (LT / 2);
        const int se = (mh == 0) ? (LT / 2) : LT;
#pragma unroll
        for (int s = sb; s < se; ++s) stage(s, p ^ 1, toff);
      }
      bf16x8 af[4][2];
#pragma unroll
      for (int mm = 0; mm < 4; ++mm) {
        const int ra = wr * 128 + (mh * 4 + mm) * 16 + l15;
        af[mm][0] = *(const bf16x8*)(Ab + ra * 64 + g0);
        af[mm][1] = *(const bf16x8*)(Ab + ra * 64 + g1);
      }
      __builtin_amdgcn_s_setprio(1);
#pragma unroll
      for (int mm = 0; mm < 4; ++mm)
#pragma unroll
        for (int nn = 0; nn < NF; ++nn) {
          acc[mh*4+mm][nn] = __builtin_amdgcn_mfma_f32_16x16x32_bf16(
              af[mm][0], ball[nn][0], acc[mh*4+mm][nn], 0, 0, 0);
          acc[mh*4+mm][nn] = __builtin_amdgcn_mfma_f32_16x16x32_bf16(
              af[mm][1], ball[nn][1], acc[mh*4+mm][nn], 0, 0, 0);
        }
      __builtin_amdgcn_s_setprio(0);
    }
    if (more) {
      asm volatile("s_waitcnt vmcnt(0)" ::: "memory");
      __syncthreads();
    }
  }

#pragma unroll
  for (int m = 0; m < 8; ++m) {
    const int row = bm + wr * 128 + m * 16 + l4 * 4;
#pragma unroll
    for (int n = 0; n < NF; ++n) {
      const int col = bn + wc * WCOLS + n * 16 + l15;
#pragma unroll
      for (int r = 0; r < 4; ++r)
        Cout[(int64_t)(row + r) * N + col] = (OutT)acc[m][n][r];
    }
  }
}

// ---------------- gemm_out8p: 8-phase + counted-vmcnt GEMM (the T3+T4 combo) ----------------
// BM=256, BN=128, BK=64, 8 waves, 3 LDS buffers (144 KB). Per K-tile: 4 quadrant
// phases, each {ds_read frags | stage unit of t+2 -> s_barrier -> lgkmcnt(0)+
// sched_barrier -> setprio + 8 MFMA + setprio -> s_barrier}. Quadrant order
// (0,0),(0,1),(1,1),(1,0): phase 3 reads nothing. vmcnt(6) ONLY at phase-3 end
// (waits loads issued 2 tiles ago; t+1's 6 loads cross the tile barrier in flight).
__global__ __launch_bounds__(512, 2) void gemm_out8p(const bf16_t* __restrict__ A,
                                                     const bf16_t* __restrict__ Bt,
                                                     float* __restrict__ Cout,
                                                     int N, int K) {
  constexpr int WCOLS = 32, NF = 2;

  __shared__ bf16_t As[3][256 * 64];   // 96 KB
  __shared__ bf16_t Bs[3][128 * 64];   // 48 KB

  const int tid = threadIdx.x;
  const int w = tid >> 6, lane = tid & 63;
  const int l15 = lane & 15, l4 = lane >> 4;
  const int wr = w >> 2, wc = w & 3;

  const int nX = gridDim.x;
  const int lin = blockIdx.y * nX + blockIdx.x;
  const int cpx = (nX * gridDim.y) >> 3;
  const int swz = (lin & 7) * cpx + (lin >> 3);
  const int bm = (swz / nX) * 256, bn = (swz % nX) * 128;

  const int rw = w * 8 + (lane >> 3);
  const int srcg = ((lane & 7) ^ ((lane >> 3) & 7)) << 3;
  const bf16_t* PA[4];
  const bf16_t* PB[2];
#pragma unroll
  for (int L = 0; L < 4; ++L)
    PA[L] = A + (int64_t)(bm + L * 64 + rw) * K + srcg;
#pragma unroll
  for (int L = 0; L < 2; ++L)
    PB[L] = Bt + (int64_t)(bn + L * 64 + rw) * K + srcg;

  const int NK = K >> 6;
  const int xr = l15 & 7;
  const int g0 = (l4 ^ xr) << 3;
  const int g1 = ((4 + l4) ^ xr) << 3;

  f32x4 acc[8][NF] = {};

  // stage unit u of tile tsrc: u=0 -> A rows 0-127, u=1 -> A rows 128-255, u=2 -> B.
  // Always exactly 2 loads (uniform vmcnt); tail clamped.
  auto stageu = [&](int tsrc, int buf, int u) {
    const int tc = (tsrc < NK) ? tsrc : (NK - 1);
    const int toff = tc << 6;
    if (u < 2) {
      gload_lds16(PA[2*u]     + toff, &As[buf][(2*u)     * 4096 + w * 512]);
      gload_lds16(PA[2*u + 1] + toff, &As[buf][(2*u + 1) * 4096 + w * 512]);
    } else {
      gload_lds16(PB[0] + toff, &Bs[buf][w * 512]);
      gload_lds16(PB[1] + toff, &Bs[buf][4096 + w * 512]);
    }
  };
  auto readA = [&](bf16x8 (&af)[4][2], const bf16_t* Ab, int mh) {
#pragma unroll
    for (int mm = 0; mm < 4; ++mm) {
      const int ra = wr * 128 + (mh * 4 + mm) * 16 + l15;
      af[mm][0] = *(const bf16x8*)(Ab + ra * 64 + g0);
      af[mm][1] = *(const bf16x8*)(Ab + ra * 64 + g1);
    }
  };
  auto readB = [&](bf16x8 (&bf)[2], const bf16_t* Bb, int nf) {
    const int rb = wc * WCOLS + nf * 16 + l15;
    bf[0] = *(const bf16x8*)(Bb + rb * 64 + g0);
    bf[1] = *(const bf16x8*)(Bb + rb * 64 + g1);
  };
  auto mfma8 = [&](bf16x8 (&af)[4][2], bf16x8 (&bf)[2], int mh, int nf) {
    __builtin_amdgcn_s_setprio(1);
#pragma unroll
    for (int mm = 0; mm < 4; ++mm) {
      acc[mh*4+mm][nf] = __builtin_amdgcn_mfma_f32_16x16x32_bf16(
          af[mm][0], bf[0], acc[mh*4+mm][nf], 0, 0, 0);
      acc[mh*4+mm][nf] = __builtin_amdgcn_mfma_f32_16x16x32_bf16(
          af[mm][1], bf[1], acc[mh*4+mm][nf], 0, 0, 0);
    }
    __builtin_amdgcn_s_setprio(0);
  };
  auto wait_lds = [&]() {
    asm volatile("s_waitcnt lgkmcnt(0)" ::: "memory");
    __builtin_amdgcn_sched_barrier(0);   // rule #18
  };

  // prologue: tiles 0,1 fully staged (12 loads in flight)
#pragma unroll
  for (int u = 0; u < 3; ++u) stageu(0, 0, u);
#pragma unroll
  for (int u = 0; u < 3; ++u) stageu(1, 1, u);
  asm volatile("s_waitcnt vmcnt(6)" ::: "memory");   // tile 0 landed, tile 1 in flight
  asm volatile("s_barrier" ::: "memory");

  for (int t = 0; t < NK; ++t) {
    const int cb = t % 3, nb = (t + 2) % 3;
    const bf16_t* Ab = &As[cb][0];
    const bf16_t* Bb = &Bs[cb][0];
    bf16x8 aH[4][2], bf0[2], bf1[2];

    // phase 0: A[mh0] + B[n0] reads | stage u0 of t+2
    readA(aH, Ab, 0);
    readB(bf0, Bb, 0);
    stageu(t + 2, nb, 0);
    asm volatile("s_barrier" ::: "memory");
    wait_lds();
    mfma8(aH, bf0, 0, 0);
    asm volatile("s_barrier" ::: "memory");

    // phase 1: B[n1] reads | stage u1
    readB(bf1, Bb, 1);
    stageu(t + 2, nb, 1);
    asm volatile("s_barrier" ::: "memory");
    wait_lds();
    mfma8(aH, bf1, 0, 1);
    asm volatile("s_barrier" ::: "memory");

    // phase 2: A[mh1] reads | stage u2
    readA(aH, Ab, 1);
    stageu(t + 2, nb, 2);
    asm volatile("s_barrier" ::: "memory");
    wait_lds();
    mfma8(aH, bf1, 1, 1);
    asm volatile("s_barrier" ::: "memory");

    // phase 3: no reads (A[mh1], B[n0] live) | counted wait, never vmcnt(0)
    mfma8(aH, bf0, 1, 0);
    asm volatile("s_waitcnt vmcnt(6)" ::: "memory");  // tile t+1's 6 stay in flight
    asm volatile("s_barrier" ::: "memory");
  }
  asm volatile("s_waitcnt vmcnt(0)" ::: "memory");    // drain before exit

#pragma unroll
  for (int m = 0; m < 8; ++m) {
    const int row = bm + wr * 128 + m * 16 + l4 * 4;
#pragma unroll
    for (int n = 0; n < NF; ++n) {
      const int col = bn + wc * WCOLS + n * 16 + l15;
#pragma unroll
      for (int r = 0; r < 4; ++r)
        Cout[(int64_t)(row + r) * N + col] = acc[m][n][r];
    }
  }
}

// ---------------- flash attention: paired chunks + MFMA denominators ----------------
#define SHIFT_ 8.0f
__global__ __launch_bounds__(256, 2) void attn9(const bf16_t* __restrict__ Q,
                                                const bf16_t* __restrict__ Kr,
                                                const bf16_t* __restrict__ Vt,
                                                bf16_t* __restrict__ AO) {
  const int bk = blockIdx.x;
  const int b = bk >> 3, kvh = bk & 7;
  const int y = blockIdx.y;               // 0..31
  const int q0A = y * 32, q0B = (63 - y) * 32;
  const int tid = threadIdx.x;
  const int w = tid >> 6, lane = tid & 63;
  const int l31 = lane & 31, hi = lane >> 5;
  const int h = kvh * 4 + w;

  __shared__ __align__(16) bf16_t Ks[3][64 * 64];
  __shared__ __align__(16) bf16_t Vs[3][64 * 64];

  const bf16_t* Kg = Kr + (int64_t)(b * KV_ + kvh) * S_ * HD_;
  const bf16_t* Vg = Vt + (int64_t)(b * KV_ + kvh) * HD_ * S_;

  const int rL = (w << 3) + (lane >> 3);
  const int sgr = ((lane & 7) ^ (rL & 7)) << 3;
  const bf16_t* Ksrc = Kg + (int64_t)rL * HD_ + sgr;
  const bf16_t* Vsrc = Vg + (int64_t)rL * S_ + sgr;

  const int NT = (63 - y) / 2 + 1;

  auto stage = [&](int t) {
    const int tc = (t < NT) ? t : (NT - 1);
    char* Kd = (char*)Ks + (t % 3) * 8192 + w * 1024;
    char* Vd = (char*)Vs + (t % 3) * 8192 + w * 1024;
    gload_lds16(Ksrc + (int64_t)tc * 64 * HD_, Kd);
    gload_lds16(Ksrc + (int64_t)(tc * 64 + 32) * HD_, Kd + 4096);
    gload_lds16(Vsrc + tc * 64, Vd);
    gload_lds16(Vsrc + (int64_t)32 * S_ + tc * 64, Vd + 4096);
  };

  const bf16_t* QbA = Q + ((int64_t)(b * H_ + h) * S_ + q0A) * HD_;
  const bf16_t* QbB = Q + ((int64_t)(b * H_ + h) * S_ + q0B) * HD_;
  bf16x8 qfA[4], qfB[4];
#pragma unroll
  for (int ds = 0; ds < 4; ++ds) {
    qfA[ds] = *(const bf16x8*)(QbA + l31 * HD_ + ds * 16 + hi * 8);
    qfB[ds] = *(const bf16x8*)(QbB + l31 * HD_ + ds * 16 + hi * 8);
  }

  bf16x8 onesf;
#pragma unroll
  for (int i = 0; i < 8; ++i) onesf[i] = (bf16_t)1.0f;

  f32x16 aA0 = {}, aA1 = {}, aB0 = {}, aB1 = {};
  f32x16 lA = {}, lB = {};
  const int xorb = l31 & 7;

  const f32x16 sinit = {-SHIFT_, -SHIFT_, -SHIFT_, -SHIFT_,
                        -SHIFT_, -SHIFT_, -SHIFT_, -SHIFT_,
                        -SHIFT_, -SHIFT_, -SHIFT_, -SHIFT_,
                        -SHIFT_, -SHIFT_, -SHIFT_, -SHIFT_};

  auto softmax_pack = [&](const f32x16 &sacc, bool diag,
                          bf16x8 &pf0, bf16x8 &pf1) {
    float p[16];
#pragma unroll
    for (int r = 0; r < 16; ++r) {
      float sc = sacc[r];
      if (diag) {
        int kvpos = (r & 3) + 8 * (r >> 2) + 4 * hi;
        if (kvpos > l31) sc = -1e30f;
      }
      p[r] = __builtin_amdgcn_exp2f(sc);
    }
    u32 pk[8];
#pragma unroll
    for (int i = 0; i < 8; ++i) pk[i] = pkbf(p[2*i], p[2*i+1]);
    u32 a0 = pk[0], b0 = pk[2]; pl32swap(a0, b0);
    u32 a1 = pk[1], b1 = pk[3]; pl32swap(a1, b1);
    u32 a2 = pk[4], b2 = pk[6]; pl32swap(a2, b2);
    u32 a3 = pk[5], b3 = pk[7]; pl32swap(a3, b3);
    pf0 = __builtin_bit_cast(bf16x8, (u32x4){a0, a1, b0, b1});
    pf1 = __builtin_bit_cast(bf16x8, (u32x4){a2, a3, b2, b3});
  };

  stage(0);
  stage(1);

  for (int t = 0; t < NT; ++t) {
    asm volatile("s_waitcnt vmcnt(4) lgkmcnt(0)" ::: "memory");
    asm volatile("s_barrier" ::: "memory");
    stage(t + 2);
    const char* KsB = (const char*)Ks + (t % 3) * 8192;
    const char* VsB = (const char*)Vs + (t % 3) * 8192;
#pragma unroll
    for (int sub = 0; sub < 2; ++sub) {
      const int kvbase = t * 64 + sub * 32;
      if (kvbase <= q0B) {
        const bool actA = (kvbase <= q0A);
        const char* Kbase = KsB + (sub * 32 + l31) * 128;
        bf16x8 kf[4];
#pragma unroll
        for (int ds = 0; ds < 4; ++ds)
          kf[ds] = *(const bf16x8*)(Kbase + ((((ds << 1) + hi) ^ xorb) << 4));
        f32x16 sA = sinit, sB = sinit;
        __builtin_amdgcn_s_setprio(1);
#pragma unroll
        for (int ds = 0; ds < 4; ++ds)
          sB = __builtin_amdgcn_mfma_f32_32x32x16_bf16(kf[ds], qfB[ds], sB, 0, 0, 0);
        if (actA) {
#pragma unroll
          for (int ds = 0; ds < 4; ++ds)
            sA = __builtin_amdgcn_mfma_f32_32x32x16_bf16(kf[ds], qfA[ds], sA, 0, 0, 0);
        }
        __builtin_amdgcn_s_setprio(0);
        const char* Vb0 = VsB + l31 * 128;
        const char* Vb1 = VsB + (32 + l31) * 128;
        const int c0 = (sub << 2) + hi;
        const int c1 = c0 + 2;
        bf16x8 v00 = *(const bf16x8*)(Vb0 + ((c0 ^ xorb) << 4));
        bf16x8 v01 = *(const bf16x8*)(Vb0 + ((c1 ^ xorb) << 4));
        bf16x8 v10 = *(const bf16x8*)(Vb1 + ((c0 ^ xorb) << 4));
        bf16x8 v11 = *(const bf16x8*)(Vb1 + ((c1 ^ xorb) << 4));
        bf16x8 pB0, pB1;
        softmax_pack(sB, kvbase == q0B, pB0, pB1);
        __builtin_amdgcn_s_setprio(1);
        aB0 = __builtin_amdgcn_mfma_f32_32x32x16_bf16(v00, pB0, aB0, 0, 0, 0);
        aB1 = __builtin_amdgcn_mfma_f32_32x32x16_bf16(v10, pB0, aB1, 0, 0, 0);
        aB0 = __builtin_amdgcn_mfma_f32_32x32x16_bf16(v01, pB1, aB0, 0, 0, 0);
        aB1 = __builtin_amdgcn_mfma_f32_32x32x16_bf16(v11, pB1, aB1, 0, 0, 0);
        lB  = __builtin_amdgcn_mfma_f32_32x32x16_bf16(onesf, pB0, lB, 0, 0, 0);
        lB  = __builtin_amdgcn_mfma_f32_32x32x16_bf16(onesf, pB1, lB, 0, 0, 0);
        __builtin_amdgcn_s_setprio(0);
        if (actA) {
          bf16x8 pA0, pA1;
          softmax_pack(sA, kvbase == q0A, pA0, pA1);
          __builtin_amdgcn_s_setprio(1);
          aA0 = __builtin_amdgcn_mfma_f32_32x32x16_bf16(v00, pA0, aA0, 0, 0, 0);
          aA1 = __builtin_amdgcn_mfma_f32_32x32x16_bf16(v10, pA0, aA1, 0, 0, 0);
          aA0 = __builtin_amdgcn_mfma_f32_32x32x16_bf16(v01, pA1, aA0, 0, 0, 0);
          aA1 = __builtin_amdgcn_mfma_f32_32x32x16_bf16(v11, pA1, aA1, 0, 0, 0);
          lA  = __builtin_amdgcn_mfma_f32_32x32x16_bf16(onesf, pA0, lA, 0, 0, 0);
          lA  = __builtin_amdgcn_mfma_f32_32x32x16_bf16(onesf, pA1, lA, 0, 0, 0);
          __builtin_amdgcn_s_setprio(0);
        }
      }
    }
  }

  asm volatile("s_waitcnt vmcnt(0)" ::: "memory");

  auto epi = [&](const f32x16 &a0, const f32x16 &a1, float denom, int q0) {
    const float rl = 1.f / denom;
    const int64_t row = (int64_t)(b * S_ + q0 + l31);
#pragma unroll
    for (int dt = 0; dt < 2; ++dt) {
#pragma unroll
      for (int g = 0; g < 4; ++g) {
        bf16x4 ov;
#pragma unroll
        for (int j = 0; j < 4; ++j) {
          float val = (dt ? a1[4*g + j] : a0[4*g + j]) * rl;
          ov[j] = (bf16_t)val;
        }
        const int d0 = dt * 32 + g * 8 + hi * 4;
        *(bf16x4*)(AO + row * D_ + h * HD_ + d0) = ov;
      }
    }
  };
  epi(aA0, aA1, lA[0], q0A);
  epi(aB0, aB1, lB[0], q0B);
}

// ---------------- launcher ----------------
extern "C" void kernel_launch(void* const* d_in, const int* in_sizes, int n_in,
                              void* d_out, int out_size, void* d_ws, size_t ws_size,
                              hipStream_t stream) {
  const float* x    = (const float*)d_in[0];
  const float* cosb = (const float*)d_in[1];
  const float* sinb = (const float*)d_in[2];
  const float* Wq   = (const float*)d_in[3];
  const float* Wk   = (const float*)d_in[4];
  const float* Wv   = (const float*)d_in[5];
  const float* Wo   = (const float*)d_in[6];
  float* out = (float*)d_out;

  bf16_t* ws = (bf16_t*)d_ws;
  size_t o = 0;
  bf16_t* xb    = ws + o; o += (size_t)4096 * 2048;
  bf16_t* Wqkvt = ws + o; o += (size_t)3072 * 2048;
  bf16_t* Wot   = ws + o; o += (size_t)2048 * 2048;
  bf16_t* qkv   = ws + o; o += (size_t)4096 * 3072;
  bf16_t* Qr    = ws + o; o += (size_t)B_ * H_ * S_ * HD_;
  bf16_t* Krb   = ws + o; o += (size_t)B_ * KV_ * S_ * HD_;
  bf16_t* Vtb   = ws + o; o += (size_t)B_ * KV_ * S_ * HD_;
  bf16_t* AO    = ws + o; o += (size_t)4096 * 2048;

  // fused prep: x->bf16 + all weight transposes
  prep_all<<<18432, dim3(32, 8), 0, stream>>>(x, xb, Wq, Wk, Wv, Wo, Wqkvt, Wot);
  // QKV projection: BN=192 -> 256 blocks = 1/CU, XCD-swizzled
  gemm256<192, 2, bf16_t><<<dim3(3072/192, 4096/256), 512, 0, stream>>>(
      xb, Wqkvt, qkv, 3072, 2048);
  // fused RoPE scatter + V transpose
  scatter_all<<<6144, 256, 0, stream>>>(qkv, cosb, sinb, Qr, Krb, Vtb);
  // paired-chunk attention (best measured variant)
  attn9<<<dim3(16, 32), 256, 0, stream>>>(Qr, Krb, Vtb, AO);
  // output projection -> f32: 8-phase + counted-vmcnt (the T3+T4 combination test)
  gemm_out8p<<<dim3(2048/128, 4096/256), 512, 0, stream>>>(AO, Wot, out, 2048, 2048);
}

// Round 20
// 172.225 us; speedup vs baseline: 1.0066x; 1.0066x over previous
//
#include <hip/hip_runtime.h>
#include <hip/hip_bf16.h>
#include <stdint.h>

#define B_ 2
#define S_ 2048
#define D_ 2048
#define H_ 32
#define KV_ 8
#define HD_ 64
#define NQKV 3072   // D + 2*KV*HD

typedef __bf16 bf16_t;
typedef __bf16 bf16x8 __attribute__((ext_vector_type(8)));
typedef __bf16 bf16x4 __attribute__((ext_vector_type(4)));
typedef float  f32x4  __attribute__((ext_vector_type(4)));
typedef float  f32x16 __attribute__((ext_vector_type(16)));
typedef unsigned int u32;
typedef u32 u32x4 __attribute__((ext_vector_type(4)));

typedef const __attribute__((address_space(1))) uint32_t* gp1_t;
typedef __attribute__((address_space(3))) uint32_t* lp3_t;

// async global->LDS, 16B per lane. LDS dest is wave-uniform base + lane*16.
__device__ inline void gload_lds16(const void* g, void* l) {
  __builtin_amdgcn_global_load_lds((gp1_t)(uintptr_t)g, (lp3_t)(uint32_t)(uintptr_t)l,
                                   16, 0, 0);
}

__device__ inline u32 pkbf(float a, float b) {
  union { bf16_t h[2]; u32 u; } v;
  v.h[0] = (bf16_t)a; v.h[1] = (bf16_t)b;
  return v.u;
}

// v_permlane32_swap_b32: a = [a_lo, b_lo], b = [a_hi, b_hi]
__device__ inline void pl32swap(u32 &a, u32 &b) {
  asm("v_permlane32_swap_b32 %0, %1" : "+v"(a), "+v"(b));
}

// ---------------- fused prep: x cvt + all 4 weight transposes ----------------
__global__ void prep_all(const float* __restrict__ x, bf16_t* __restrict__ xb,
                         const float* __restrict__ Wq, const float* __restrict__ Wk,
                         const float* __restrict__ Wv, const float* __restrict__ Wo,
                         bf16_t* __restrict__ Wqkvt, bf16_t* __restrict__ Wot) {
  const int id = blockIdx.x;
  const int tid = threadIdx.y * 32 + threadIdx.x;
  if (id < 8192) {                      // x -> bf16 (2097152 float4s)
    const int i = id * 256 + tid;
    float4 v = ((const float4*)x)[i];
    bf16x4 o;
    o[0] = (bf16_t)v.x; o[1] = (bf16_t)v.y; o[2] = (bf16_t)v.z; o[3] = (bf16_t)v.w;
    ((bf16x4*)xb)[i] = o;
    return;
  }
  __shared__ float t[32][33];
  const int wid = id - 8192;
  const float* in; bf16_t* out; int C, roff, bx, by;
  if (wid < 4096)      { in = Wq; out = Wqkvt; C = 2048; roff = 0;    bx = wid & 63;          by = wid >> 6; }
  else if (wid < 5120) { in = Wk; out = Wqkvt; C = 512;  roff = 2048; bx = (wid - 4096) & 15; by = (wid - 4096) >> 4; }
  else if (wid < 6144) { in = Wv; out = Wqkvt; C = 512;  roff = 2560; bx = (wid - 5120) & 15; by = (wid - 5120) >> 4; }
  else                 { in = Wo; out = Wot;   C = 2048; roff = 0;    bx = (wid - 6144) & 63; by = (wid - 6144) >> 6; }
  const int tx = threadIdx.x, ty = threadIdx.y;   // (32,8)
  const int c0 = bx * 32, r0 = by * 32;
#pragma unroll
  for (int j = 0; j < 4; ++j)
    t[ty + j*8][tx] = in[(int64_t)(r0 + ty + j*8) * C + c0 + tx];
  __syncthreads();
#pragma unroll
  for (int j = 0; j < 4; ++j)
    out[(int64_t)(roff + c0 + ty + j*8) * 2048 + r0 + tx] = (bf16_t)t[tx][ty + j*8];
}

// ---------------- fused scatter: RoPE Q/K + V transpose ----------------
#define QSCALE 0.18033688011112042f
__global__ __launch_bounds__(256) void scatter_all(const bf16_t* __restrict__ qkv,
                                                   const float* __restrict__ cosb,
                                                   const float* __restrict__ sinb,
                                                   bf16_t* __restrict__ Q,
                                                   bf16_t* __restrict__ Kr,
                                                   bf16_t* __restrict__ Vt) {
  const int id = blockIdx.x;
  const int tid = threadIdx.x;
  if (id < 4096) {                       // RoPE rows
    const int row = id;                  // b*S + s
    const int b = row >> 11, s = row & 2047;
    const bf16_t* src = qkv + (int64_t)row * NQKV;
    const float* cs = cosb + s * HD_;
    const float* sn = sinb + s * HD_;
    {                                    // Q
      const int c0 = tid * 8;
      const int d0 = c0 & 63, h = c0 >> 6;
      bf16x8 own = *(const bf16x8*)(src + c0);
      bf16x8 par = *(const bf16x8*)(src + (c0 ^ 32));
      const float sgn = (d0 & 32) ? 1.f : -1.f;
      bf16x8 o;
#pragma unroll
      for (int j = 0; j < 8; ++j) {
        const int d = d0 + j;
        float val = (float)own[j] * cs[d] + sgn * (float)par[j] * sn[d];
        o[j] = (bf16_t)(val * QSCALE);
      }
      *(bf16x8*)(Q + ((int64_t)(b * H_ + h) * S_ + s) * HD_ + d0) = o;
    }
    if (tid < 64) {                      // K
      const int c0 = 2048 + tid * 8;
      const int d0 = (tid * 8) & 63, kvh = tid >> 3;
      bf16x8 own = *(const bf16x8*)(src + c0);
      bf16x8 par = *(const bf16x8*)(src + (c0 ^ 32));
      const float sgn = (d0 & 32) ? 1.f : -1.f;
      bf16x8 o;
#pragma unroll
      for (int j = 0; j < 8; ++j) {
        const int d = d0 + j;
        float val = (float)own[j] * cs[d] + sgn * (float)par[j] * sn[d];
        o[j] = (bf16_t)val;
      }
      *(bf16x8*)(Kr + ((int64_t)(b * KV_ + kvh) * S_ + s) * HD_ + d0) = o;
    }
    return;
  }
  // V transpose tiles
  __shared__ bf16_t t[32][34];
  const int wid = id - 4096;
  const int c0 = (wid & 15) * 32;
  const int s0 = ((wid >> 4) & 63) * 32;
  const int b  = wid >> 10;
  const int tx = tid & 31, ty = tid >> 5;   // (32,8)
#pragma unroll
  for (int j = 0; j < 4; ++j)
    t[ty + j*8][tx] = qkv[(int64_t)(b * S_ + s0 + ty + j*8) * NQKV + 2560 + c0 + tx];
  __syncthreads();
#pragma unroll
  for (int j = 0; j < 4; ++j)
    Vt[(int64_t)(b * 512 + c0 + ty + j*8) * S_ + s0 + tx] = t[tx][ty + j*8];
}

// ---------------- 256-row deep-pipelined GEMM (2-buf, XCD swizzle) ----------------
template <int BN, int EPI, typename OutT>
__global__ __launch_bounds__(512, 2) void gemm256(const bf16_t* __restrict__ A,
                                                  const bf16_t* __restrict__ Bt,
                                                  OutT* __restrict__ Cout,
                                                  int N, int K) {
  constexpr int NB = BN / 64;
  constexpr int LT = 4 + NB;
  constexpr int WCOLS = BN / 4;
  constexpr int NF = WCOLS / 16;

  __shared__ bf16_t As[2][256 * 64];
  __shared__ bf16_t Bs[2][BN * 64];

  const int tid = threadIdx.x;
  const int w = tid >> 6, lane = tid & 63;
  const int l15 = lane & 15, l4 = lane >> 4;
  const int wr = w >> 2, wc = w & 3;

  const int nX = gridDim.x;
  const int lin = blockIdx.y * nX + blockIdx.x;
  const int cpx = (nX * gridDim.y) >> 3;
  const int swz = (lin & 7) * cpx + (lin >> 3);
  const int bm = (swz / nX) * 256, bn = (swz % nX) * BN;

  const int rw = w * 8 + (lane >> 3);
  const int srcg = ((lane & 7) ^ ((lane >> 3) & 7)) << 3;
  const bf16_t* PA[4];
  const bf16_t* PB[NB];
#pragma unroll
  for (int L = 0; L < 4; ++L)
    PA[L] = A + (int64_t)(bm + L * 64 + rw) * K + srcg;
#pragma unroll
  for (int L = 0; L < NB; ++L)
    PB[L] = Bt + (int64_t)(bn + L * 64 + rw) * K + srcg;

  const int NK = K >> 6;
  const int xr = l15 & 7;
  const int g0 = (l4 ^ xr) << 3;
  const int g1 = ((4 + l4) ^ xr) << 3;

  f32x4 acc[8][NF] = {};

  auto stage = [&](int s, int buf, int toff) {
    if (s < 4) gload_lds16(PA[s] + toff, &As[buf][s * 4096 + w * 512]);
    else       gload_lds16(PB[s - 4] + toff, &Bs[buf][(s - 4) * 4096 + w * 512]);
  };

#pragma unroll
  for (int s = 0; s < LT; ++s) stage(s, 0, 0);
  asm volatile("s_waitcnt vmcnt(0)" ::: "memory");
  __syncthreads();

  for (int t = 0; t < NK; ++t) {
    const int p = t & 1;
    const bool more = (t + 1) < NK;
    const int toff = (t + 1) << 6;
    const bf16_t* Ab = &As[p][0];
    const bf16_t* Bb = &Bs[p][0];

    bf16x8 ball[NF][2];
#pragma unroll
    for (int nn = 0; nn < NF; ++nn) {
      const int rb = wc * WCOLS + nn * 16 + l15;
      ball[nn][0] = *(const bf16x8*)(Bb + rb * 64 + g0);
      ball[nn][1] = *(const bf16x8*)(Bb + rb * 64 + g1);
    }

#pragma unroll
    for (int mh = 0; mh < 2; ++mh) {
      if (more) {
        const int sb = mh * (LT / 2);
        const int se = (mh == 0) ? (LT / 2) : LT;
#pragma unroll
        for (int s = sb; s < se; ++s) stage(s, p ^ 1, toff);
      }
      bf16x8 af[4][2];
#pragma unroll
      for (int mm = 0; mm < 4; ++mm) {
        const int ra = wr * 128 + (mh * 4 + mm) * 16 + l15;
        af[mm][0] = *(const bf16x8*)(Ab + ra * 64 + g0);
        af[mm][1] = *(const bf16x8*)(Ab + ra * 64 + g1);
      }
      __builtin_amdgcn_s_setprio(1);
#pragma unroll
      for (int mm = 0; mm < 4; ++mm)
#pragma unroll
        for (int nn = 0; nn < NF; ++nn) {
          acc[mh*4+mm][nn] = __builtin_amdgcn_mfma_f32_16x16x32_bf16(
              af[mm][0], ball[nn][0], acc[mh*4+mm][nn], 0, 0, 0);
          acc[mh*4+mm][nn] = __builtin_amdgcn_mfma_f32_16x16x32_bf16(
              af[mm][1], ball[nn][1], acc[mh*4+mm][nn], 0, 0, 0);
        }
      __builtin_amdgcn_s_setprio(0);
    }
    if (more) {
      asm volatile("s_waitcnt vmcnt(0)" ::: "memory");
      __syncthreads();
    }
  }

#pragma unroll
  for (int m = 0; m < 8; ++m) {
    const int row = bm + wr * 128 + m * 16 + l4 * 4;
#pragma unroll
    for (int n = 0; n < NF; ++n) {
      const int col = bn + wc * WCOLS + n * 16 + l15;
#pragma unroll
      for (int r = 0; r < 4; ++r)
        Cout[(int64_t)(row + r) * N + col] = (OutT)acc[m][n][r];
    }
  }
}

// ---------------- flash attention: paired chunks + MFMA denominators ----------------
// grid (16 = b*8+kvh, 32 = y). 4 waves; wave w = head kvh*4+w, chunks {y, 63-y}.
// Counted vmcnt(4) + raw s_barrier: next tile's loads stay in flight across barrier.
#define SHIFT_ 8.0f
__global__ __launch_bounds__(256, 2) void attn9(const bf16_t* __restrict__ Q,
                                                const bf16_t* __restrict__ Kr,
                                                const bf16_t* __restrict__ Vt,
                                                bf16_t* __restrict__ AO) {
  const int bk = blockIdx.x;
  const int b = bk >> 3, kvh = bk & 7;
  const int y = blockIdx.y;               // 0..31
  const int q0A = y * 32, q0B = (63 - y) * 32;
  const int tid = threadIdx.x;
  const int w = tid >> 6, lane = tid & 63;
  const int l31 = lane & 31, hi = lane >> 5;
  const int h = kvh * 4 + w;

  __shared__ __align__(16) bf16_t Ks[3][64 * 64];
  __shared__ __align__(16) bf16_t Vs[3][64 * 64];

  const bf16_t* Kg = Kr + (int64_t)(b * KV_ + kvh) * S_ * HD_;
  const bf16_t* Vg = Vt + (int64_t)(b * KV_ + kvh) * HD_ * S_;

  const int rL = (w << 3) + (lane >> 3);
  const int sgr = ((lane & 7) ^ (rL & 7)) << 3;
  const bf16_t* Ksrc = Kg + (int64_t)rL * HD_ + sgr;
  const bf16_t* Vsrc = Vg + (int64_t)rL * S_ + sgr;

  const int NT = (63 - y) / 2 + 1;

  auto stage = [&](int t) {
    const int tc = (t < NT) ? t : (NT - 1);
    char* Kd = (char*)Ks + (t % 3) * 8192 + w * 1024;
    char* Vd = (char*)Vs + (t % 3) * 8192 + w * 1024;
    gload_lds16(Ksrc + (int64_t)tc * 64 * HD_, Kd);
    gload_lds16(Ksrc + (int64_t)(tc * 64 + 32) * HD_, Kd + 4096);
    gload_lds16(Vsrc + tc * 64, Vd);
    gload_lds16(Vsrc + (int64_t)32 * S_ + tc * 64, Vd + 4096);
  };

  const bf16_t* QbA = Q + ((int64_t)(b * H_ + h) * S_ + q0A) * HD_;
  const bf16_t* QbB = Q + ((int64_t)(b * H_ + h) * S_ + q0B) * HD_;
  bf16x8 qfA[4], qfB[4];
#pragma unroll
  for (int ds = 0; ds < 4; ++ds) {
    qfA[ds] = *(const bf16x8*)(QbA + l31 * HD_ + ds * 16 + hi * 8);
    qfB[ds] = *(const bf16x8*)(QbB + l31 * HD_ + ds * 16 + hi * 8);
  }

  bf16x8 onesf;
#pragma unroll
  for (int i = 0; i < 8; ++i) onesf[i] = (bf16_t)1.0f;

  f32x16 aA0 = {}, aA1 = {}, aB0 = {}, aB1 = {};
  f32x16 lA = {}, lB = {};
  const int xorb = l31 & 7;

  const f32x16 sinit = {-SHIFT_, -SHIFT_, -SHIFT_, -SHIFT_,
                        -SHIFT_, -SHIFT_, -SHIFT_, -SHIFT_,
                        -SHIFT_, -SHIFT_, -SHIFT_, -SHIFT_,
                        -SHIFT_, -SHIFT_, -SHIFT_, -SHIFT_};

  auto softmax_pack = [&](const f32x16 &sacc, bool diag,
                          bf16x8 &pf0, bf16x8 &pf1) {
    float p[16];
#pragma unroll
    for (int r = 0; r < 16; ++r) {
      float sc = sacc[r];
      if (diag) {
        int kvpos = (r & 3) + 8 * (r >> 2) + 4 * hi;
        if (kvpos > l31) sc = -1e30f;
      }
      p[r] = __builtin_amdgcn_exp2f(sc);
    }
    u32 pk[8];
#pragma unroll
    for (int i = 0; i < 8; ++i) pk[i] = pkbf(p[2*i], p[2*i+1]);
    u32 a0 = pk[0], b0 = pk[2]; pl32swap(a0, b0);
    u32 a1 = pk[1], b1 = pk[3]; pl32swap(a1, b1);
    u32 a2 = pk[4], b2 = pk[6]; pl32swap(a2, b2);
    u32 a3 = pk[5], b3 = pk[7]; pl32swap(a3, b3);
    pf0 = __builtin_bit_cast(bf16x8, (u32x4){a0, a1, b0, b1});
    pf1 = __builtin_bit_cast(bf16x8, (u32x4){a2, a3, b2, b3});
  };

  stage(0);
  stage(1);

  for (int t = 0; t < NT; ++t) {
    asm volatile("s_waitcnt vmcnt(4) lgkmcnt(0)" ::: "memory");
    asm volatile("s_barrier" ::: "memory");
    stage(t + 2);
    const char* KsB = (const char*)Ks + (t % 3) * 8192;
    const char* VsB = (const char*)Vs + (t % 3) * 8192;
#pragma unroll
    for (int sub = 0; sub < 2; ++sub) {
      const int kvbase = t * 64 + sub * 32;
      if (kvbase <= q0B) {
        const bool actA = (kvbase <= q0A);
        const char* Kbase = KsB + (sub * 32 + l31) * 128;
        bf16x8 kf[4];
#pragma unroll
        for (int ds = 0; ds < 4; ++ds)
          kf[ds] = *(const bf16x8*)(Kbase + ((((ds << 1) + hi) ^ xorb) << 4));
        f32x16 sA = sinit, sB = sinit;
        __builtin_amdgcn_s_setprio(1);
#pragma unroll
        for (int ds = 0; ds < 4; ++ds)
          sB = __builtin_amdgcn_mfma_f32_32x32x16_bf16(kf[ds], qfB[ds], sB, 0, 0, 0);
        if (actA) {
#pragma unroll
          for (int ds = 0; ds < 4; ++ds)
            sA = __builtin_amdgcn_mfma_f32_32x32x16_bf16(kf[ds], qfA[ds], sA, 0, 0, 0);
        }
        __builtin_amdgcn_s_setprio(0);
        const char* Vb0 = VsB + l31 * 128;
        const char* Vb1 = VsB + (32 + l31) * 128;
        const int c0 = (sub << 2) + hi;
        const int c1 = c0 + 2;
        bf16x8 v00 = *(const bf16x8*)(Vb0 + ((c0 ^ xorb) << 4));
        bf16x8 v01 = *(const bf16x8*)(Vb0 + ((c1 ^ xorb) << 4));
        bf16x8 v10 = *(const bf16x8*)(Vb1 + ((c0 ^ xorb) << 4));
        bf16x8 v11 = *(const bf16x8*)(Vb1 + ((c1 ^ xorb) << 4));
        bf16x8 pB0, pB1;
        softmax_pack(sB, kvbase == q0B, pB0, pB1);
        __builtin_amdgcn_s_setprio(1);
        aB0 = __builtin_amdgcn_mfma_f32_32x32x16_bf16(v00, pB0, aB0, 0, 0, 0);
        aB1 = __builtin_amdgcn_mfma_f32_32x32x16_bf16(v10, pB0, aB1, 0, 0, 0);
        aB0 = __builtin_amdgcn_mfma_f32_32x32x16_bf16(v01, pB1, aB0, 0, 0, 0);
        aB1 = __builtin_amdgcn_mfma_f32_32x32x16_bf16(v11, pB1, aB1, 0, 0, 0);
        lB  = __builtin_amdgcn_mfma_f32_32x32x16_bf16(onesf, pB0, lB, 0, 0, 0);
        lB  = __builtin_amdgcn_mfma_f32_32x32x16_bf16(onesf, pB1, lB, 0, 0, 0);
        __builtin_amdgcn_s_setprio(0);
        if (actA) {
          bf16x8 pA0, pA1;
          softmax_pack(sA, kvbase == q0A, pA0, pA1);
          __builtin_amdgcn_s_setprio(1);
          aA0 = __builtin_amdgcn_mfma_f32_32x32x16_bf16(v00, pA0, aA0, 0, 0, 0);
          aA1 = __builtin_amdgcn_mfma_f32_32x32x16_bf16(v10, pA0, aA1, 0, 0, 0);
          aA0 = __builtin_amdgcn_mfma_f32_32x32x16_bf16(v01, pA1, aA0, 0, 0, 0);
          aA1 = __builtin_amdgcn_mfma_f32_32x32x16_bf16(v11, pA1, aA1, 0, 0, 0);
          lA  = __builtin_amdgcn_mfma_f32_32x32x16_bf16(onesf, pA0, lA, 0, 0, 0);
          lA  = __builtin_amdgcn_mfma_f32_32x32x16_bf16(onesf, pA1, lA, 0, 0, 0);
          __builtin_amdgcn_s_setprio(0);
        }
      }
    }
  }

  asm volatile("s_waitcnt vmcnt(0)" ::: "memory");

  auto epi = [&](const f32x16 &a0, const f32x16 &a1, float denom, int q0) {
    const float rl = 1.f / denom;
    const int64_t row = (int64_t)(b * S_ + q0 + l31);
#pragma unroll
    for (int dt = 0; dt < 2; ++dt) {
#pragma unroll
      for (int g = 0; g < 4; ++g) {
        bf16x4 ov;
#pragma unroll
        for (int j = 0; j < 4; ++j) {
          float val = (dt ? a1[4*g + j] : a0[4*g + j]) * rl;
          ov[j] = (bf16_t)val;
        }
        const int d0 = dt * 32 + g * 8 + hi * 4;
        *(bf16x4*)(AO + row * D_ + h * HD_ + d0) = ov;
      }
    }
  };
  epi(aA0, aA1, lA[0], q0A);
  epi(aB0, aB1, lB[0], q0B);
}

// ---------------- launcher ----------------
extern "C" void kernel_launch(void* const* d_in, const int* in_sizes, int n_in,
                              void* d_out, int out_size, void* d_ws, size_t ws_size,
                              hipStream_t stream) {
  const float* x    = (const float*)d_in[0];
  const float* cosb = (const float*)d_in[1];
  const float* sinb = (const float*)d_in[2];
  const float* Wq   = (const float*)d_in[3];
  const float* Wk   = (const float*)d_in[4];
  const float* Wv   = (const float*)d_in[5];
  const float* Wo   = (const float*)d_in[6];
  float* out = (float*)d_out;

  bf16_t* ws = (bf16_t*)d_ws;
  size_t o = 0;
  bf16_t* xb    = ws + o; o += (size_t)4096 * 2048;
  bf16_t* Wqkvt = ws + o; o += (size_t)3072 * 2048;
  bf16_t* Wot   = ws + o; o += (size_t)2048 * 2048;
  bf16_t* qkv   = ws + o; o += (size_t)4096 * 3072;
  bf16_t* Qr    = ws + o; o += (size_t)B_ * H_ * S_ * HD_;
  bf16_t* Krb   = ws + o; o += (size_t)B_ * KV_ * S_ * HD_;
  bf16_t* Vtb   = ws + o; o += (size_t)B_ * KV_ * S_ * HD_;
  bf16_t* AO    = ws + o; o += (size_t)4096 * 2048;

  // fused prep: x->bf16 + all weight transposes
  prep_all<<<18432, dim3(32, 8), 0, stream>>>(x, xb, Wq, Wk, Wv, Wo, Wqkvt, Wot);
  // QKV projection: BN=192 -> 256 blocks = 1/CU, XCD-swizzled
  gemm256<192, 2, bf16_t><<<dim3(3072/192, 4096/256), 512, 0, stream>>>(
      xb, Wqkvt, qkv, 3072, 2048);
  // fused RoPE scatter + V transpose
  scatter_all<<<6144, 256, 0, stream>>>(qkv, cosb, sinb, Qr, Krb, Vtb);
  // paired-chunk attention (best measured variant)
  attn9<<<dim3(16, 32), 256, 0, stream>>>(Qr, Krb, Vtb, AO);
  // output projection -> f32 (BN=128 -> 256 blocks = 1/CU, XCD-swizzled)
  gemm256<128, 0, float><<<dim3(2048/128, 4096/256), 512, 0, stream>>>(
      AO, Wot, out, 2048, 2048);
}